// Round 10
// baseline (746.855 us; speedup 1.0000x reference)
//
#include <hip/hip_runtime.h>
#include <hip/hip_bf16.h>
#include <cmath>

// Problem constants
#define B_    4
#define T_    2048
#define DIM_  1024
#define H_    16
#define NOPE_ 128
#define ROPE_ 64
#define VDIM_ 128
#define KVR_  512
#define QKD_  192          // NOPE + ROPE
#define NTOK  (B_ * T_)    // 8192

static constexpr float SCALE_  = 0.07216878364870322f;            // 1/sqrt(192)
static constexpr float SCALE2_ = 0.07216878364870322f * 1.4426950408889634f; // fold log2(e): softmax in base-2

typedef __attribute__((ext_vector_type(8))) unsigned short ushort8_t;
typedef __bf16 v8bf __attribute__((ext_vector_type(8)));
typedef float  v4f  __attribute__((ext_vector_type(4)));

__device__ __forceinline__ float bf2f(unsigned short u) {
    return __uint_as_float(((unsigned int)u) << 16);
}
// round-to-nearest-even f32 -> bf16 bits (finite inputs)
__device__ __forceinline__ unsigned short f2bf(float f) {
    unsigned int u = __float_as_uint(f);
    u += 0x7FFFu + ((u >> 16) & 1u);
    return (unsigned short)(u >> 16);
}
__device__ __forceinline__ void store1(float* p, float v)          { *p = v; }
__device__ __forceinline__ void store1(__hip_bfloat16* p, float v) { *p = __float2bfloat16(v); }

// async global->LDS, 16B per lane. LDS dest = wave-uniform base + lane*16.
__device__ __forceinline__ void load_lds16(const void* g, void* l) {
    __builtin_amdgcn_global_load_lds(
        (const __attribute__((address_space(1))) void*)g,
        (__attribute__((address_space(3))) void*)l, 16, 0, 0);
}

__device__ __forceinline__ void cvt4(const float* s, __hip_bfloat16* d, int q4) {
    const int i = q4 * 4;
    const float4 v = *(const float4*)(s + i);
    ushort4 o;
    o.x = f2bf(v.x); o.y = f2bf(v.y); o.z = f2bf(v.z); o.w = f2bf(v.w);
    *(ushort4*)((unsigned short*)d + i) = o;
}

// ---------------------------------------------------------------------------
// ONE kernel for all fp32->bf16 conversions (x, wq, wkvb, wo, wkva-padded +
// padded bias). Merging 5 launches -> 1 (launch overhead was ~5-10us each).
// Segment sizes in float4 quads.
// ---------------------------------------------------------------------------
#define X4_   (NTOK*1024/4)     // 2,097,152
#define Q4_   (3072*1024/4)     //   786,432
#define KB4_  (4096*512/4)      //   524,288
#define O4_   (1024*2048/4)     //   524,288
#define A4_   (640*1024/4)      //   163,840
#define CVT_TOTAL (X4_ + Q4_ + KB4_ + O4_ + A4_)   // 4,096,000 -> 16,000 blocks

__global__ __launch_bounds__(256) void cvt_all(
    const float* __restrict__ x,    const float* __restrict__ wq,
    const float* __restrict__ wkvb, const float* __restrict__ wo,
    const float* __restrict__ wkva, const float* __restrict__ wkva_bias,
    __hip_bfloat16* __restrict__ xb,    __hip_bfloat16* __restrict__ wqb,
    __hip_bfloat16* __restrict__ wkvbb, __hip_bfloat16* __restrict__ wob,
    __hip_bfloat16* __restrict__ wkvab, float* __restrict__ bias_pad)
{
    int idx = blockIdx.x * 256 + threadIdx.x;
    if (idx < X4_) { cvt4(x, xb, idx); return; }
    idx -= X4_;
    if (idx < Q4_) { cvt4(wq, wqb, idx); return; }
    idx -= Q4_;
    if (idx < KB4_) { cvt4(wkvb, wkvbb, idx); return; }
    idx -= KB4_;
    if (idx < O4_) { cvt4(wo, wob, idx); return; }
    idx -= O4_;
    if (idx < A4_) {
        const int i = idx * 4;
        ushort4 o;
        if (i < 576 * 1024) {
            const float4 v = *(const float4*)(wkva + i);
            o.x = f2bf(v.x); o.y = f2bf(v.y); o.z = f2bf(v.z); o.w = f2bf(v.w);
        } else {
            o.x = o.y = o.z = o.w = 0;
        }
        *(ushort4*)((unsigned short*)wkvab + i) = o;
        if (idx < 640) bias_pad[idx] = (idx < 576) ? wkva_bias[idx] : 0.0f;
    }
}

// ---------------------------------------------------------------------------
// MFMA GEMM: C[m][n] = sum_k A[m][k]*W[n][k] + bias[n]. A,W bf16, acc fp32.
// Tiles 128x128xBK32, 4 waves (2x2 of 64x64), 16x16x32 MFMA.
// EPI=0: plain store to C.
// EPI=1: kv_b split epilogue: even 128-tiles -> kn; odd tiles -> vt via an
//        LDS-bounce transpose (XOR-swizzled, 2-way banks both sides) so the
//        global vt stores are coalesced 256B rows instead of 8B scatters.
// ---------------------------------------------------------------------------
template <typename CT, int EPI>
__global__ __launch_bounds__(256) void gemm_mfma(
    const __hip_bfloat16* __restrict__ A, int lda,
    const __hip_bfloat16* __restrict__ W, int ldw,
    const float* __restrict__ bias,
    CT* __restrict__ C, int ldc, int K,
    __hip_bfloat16* __restrict__ vt)
{
    __shared__ unsigned short smem[2 * 128 * 32];   // A tile | B tile (16 KB)
    unsigned short* A_s = smem;
    unsigned short* B_s = smem + 128 * 32;

    const int tid  = threadIdx.x;
    const int ln   = tid & 63;
    const int wv   = tid >> 6;
    const int l15  = ln & 15;
    const int quad = ln >> 4;
    const int wm   = wv & 1, wn = wv >> 1;
    const int n0 = blockIdx.x * 128, m0 = blockIdx.y * 128;

    v4f acc[4][4] = {};

    for (int k0 = 0; k0 < K; k0 += 32) {
        __syncthreads();
        #pragma unroll
        for (int it = 0; it < 2; ++it) {
            const int idx = it * 256 + wv * 64;   // wave-uniform LDS slot base
            const int li  = idx + ln;
            const int row = li >> 2, ch = li & 3;
            load_lds16(A + (size_t)(m0 + row) * lda + k0 + ch * 8, &A_s[idx * 8]);
            load_lds16(W + (size_t)(n0 + row) * ldw + k0 + ch * 8, &B_s[idx * 8]);
        }
        __syncthreads();

        v8bf af[4], bf_[4];
        #pragma unroll
        for (int i = 0; i < 4; ++i) {
            af[i]  = *(const v8bf*)&A_s[(wm * 64 + i * 16 + l15) * 32 + quad * 8];
            bf_[i] = *(const v8bf*)&B_s[(wn * 64 + i * 16 + l15) * 32 + quad * 8];
        }
        #pragma unroll
        for (int i = 0; i < 4; ++i)
            #pragma unroll
            for (int j = 0; j < 4; ++j)
                acc[i][j] = __builtin_amdgcn_mfma_f32_16x16x32_bf16(
                                af[i], bf_[j], acc[i][j], 0, 0, 0);
    }

    if (EPI == 0) {
        #pragma unroll
        for (int i = 0; i < 4; ++i) {
            const int mrow = m0 + wm * 64 + i * 16 + quad * 4;
            #pragma unroll
            for (int j = 0; j < 4; ++j) {
                const int ncol = n0 + wn * 64 + j * 16 + l15;
                const float bb = bias[ncol];
                #pragma unroll
                for (int r = 0; r < 4; ++r)
                    store1(C + (size_t)(mrow + r) * ldc + ncol, acc[i][j][r] + bb);
            }
        }
    } else {
        const int head = n0 >> 8;
        const bool is_v = (n0 & 128) != 0;
        if (!is_v) {
            #pragma unroll
            for (int i = 0; i < 4; ++i) {
                const int mrow = m0 + wm * 64 + i * 16 + quad * 4;
                #pragma unroll
                for (int j = 0; j < 4; ++j) {
                    const int ncl = wn * 64 + j * 16 + l15;
                    const float bb = bias[n0 + ncl];
                    __hip_bfloat16* kn = (__hip_bfloat16*)C;
                    #pragma unroll
                    for (int r = 0; r < 4; ++r)
                        kn[(size_t)(mrow + r) * 2048 + head * 128 + ncl] =
                            __float2bfloat16(acc[i][j][r] + bb);
                }
            }
        } else {
            // V tile: transpose via LDS in two 64-row passes, coalesced stores.
            __syncthreads();   // all waves finished reading A_s/B_s
            #pragma unroll
            for (int p = 0; p < 2; ++p) {
                if (p) __syncthreads();    // pass-0 stores done before overwrite
                if (wn == p) {
                    #pragma unroll
                    for (int i = 0; i < 4; ++i) {
                        #pragma unroll
                        for (int j = 0; j < 4; ++j) {
                            const int nl = j * 16 + l15;       // 0..63 in half
                            const float bb = bias[n0 + p*64 + nl];
                            const int ml = wm * 64 + i * 16 + quad * 4;
                            // XOR swizzle at 8-ushort granularity (2-way banks)
                            const int seg = (ml >> 3) ^ (nl & 15);
                            ushort4 pk;
                            pk.x = f2bf(acc[i][j][0] + bb);
                            pk.y = f2bf(acc[i][j][1] + bb);
                            pk.z = f2bf(acc[i][j][2] + bb);
                            pk.w = f2bf(acc[i][j][3] + bb);
                            *(ushort4*)&smem[nl * 128 + seg * 8 + (ml & 7)] = pk;
                        }
                    }
                }
                __syncthreads();
                // store 64 rows (vd) x 128 toks, 256B per row, unswizzle read
                #pragma unroll
                for (int it = 0; it < 4; ++it) {
                    const int flat = tid + it * 256;
                    const int row = flat >> 4, seg = flat & 15;
                    const int vd = head * 128 + p * 64 + row;
                    *(ushort8_t*)((unsigned short*)vt + (size_t)vd * NTOK + m0 + seg * 8)
                        = *(const ushort8_t*)&smem[row * 128 + (seg ^ (row & 15)) * 8];
                }
            }
        }
    }
}

// ---------------------------------------------------------------------------
// Fused q-proj + kva-proj (same A operand, K=1024): one launch, branch on bx.
// bx < 24: q tile (N=3072). bx >= 24: kva tile (N=640 padded).
// ---------------------------------------------------------------------------
__global__ __launch_bounds__(256) void gemm_qkva(
    const __hip_bfloat16* __restrict__ A,
    const __hip_bfloat16* __restrict__ Wq, const float* __restrict__ biasq,
    __hip_bfloat16* __restrict__ Cq,
    const __hip_bfloat16* __restrict__ Wa, const float* __restrict__ biasa,
    __hip_bfloat16* __restrict__ Ca)
{
    __shared__ unsigned short smem[2 * 128 * 32];
    unsigned short* A_s = smem;
    unsigned short* B_s = smem + 128 * 32;

    const bool is_q = blockIdx.x < 24;
    const __hip_bfloat16* W = is_q ? Wq : Wa;
    const float* bias       = is_q ? biasq : biasa;
    __hip_bfloat16* C       = is_q ? Cq : Ca;
    const int ldc = is_q ? 3072 : 640;
    const int n0  = (is_q ? blockIdx.x : (blockIdx.x - 24)) * 128;
    const int m0  = blockIdx.y * 128;

    const int tid  = threadIdx.x;
    const int ln   = tid & 63;
    const int wv   = tid >> 6;
    const int l15  = ln & 15;
    const int quad = ln >> 4;
    const int wm   = wv & 1, wn = wv >> 1;

    v4f acc[4][4] = {};

    for (int k0 = 0; k0 < 1024; k0 += 32) {
        __syncthreads();
        #pragma unroll
        for (int it = 0; it < 2; ++it) {
            const int idx = it * 256 + wv * 64;
            const int li  = idx + ln;
            const int row = li >> 2, ch = li & 3;
            load_lds16(A + (size_t)(m0 + row) * 1024 + k0 + ch * 8, &A_s[idx * 8]);
            load_lds16(W + (size_t)(n0 + row) * 1024 + k0 + ch * 8, &B_s[idx * 8]);
        }
        __syncthreads();

        v8bf af[4], bf_[4];
        #pragma unroll
        for (int i = 0; i < 4; ++i) {
            af[i]  = *(const v8bf*)&A_s[(wm * 64 + i * 16 + l15) * 32 + quad * 8];
            bf_[i] = *(const v8bf*)&B_s[(wn * 64 + i * 16 + l15) * 32 + quad * 8];
        }
        #pragma unroll
        for (int i = 0; i < 4; ++i)
            #pragma unroll
            for (int j = 0; j < 4; ++j)
                acc[i][j] = __builtin_amdgcn_mfma_f32_16x16x32_bf16(
                                af[i], bf_[j], acc[i][j], 0, 0, 0);
    }

    #pragma unroll
    for (int i = 0; i < 4; ++i) {
        const int mrow = m0 + wm * 64 + i * 16 + quad * 4;
        #pragma unroll
        for (int j = 0; j < 4; ++j) {
            const int ncol = n0 + wn * 64 + j * 16 + l15;
            const float bb = bias[ncol];
            #pragma unroll
            for (int r = 0; r < 4; ++r)
                C[(size_t)(mrow + r) * ldc + ncol] = __float2bfloat16(acc[i][j][r] + bb);
        }
    }
}

// ---------------------------------------------------------------------------
// RMS-norm kv_a[:,0:512] -> kvn bf16; RoPE kv_a[:,512:576] -> kr bf16.
// ---------------------------------------------------------------------------
__global__ __launch_bounds__(256) void rmsnorm_ropek(
    const __hip_bfloat16* __restrict__ kva,
    __hip_bfloat16* __restrict__ kvn,
    __hip_bfloat16* __restrict__ kr,
    const float* __restrict__ cs,
    const float* __restrict__ sn)
{
    const int tok = blockIdx.x;
    const int tid = threadIdx.x;
    const __hip_bfloat16* row = kva + (size_t)tok * 640;

    const float x0 = __bfloat162float(row[tid]);
    const float x1 = __bfloat162float(row[tid + 256]);
    float ss = x0*x0 + x1*x1;
    #pragma unroll
    for (int off = 32; off >= 1; off >>= 1)
        ss += __shfl_down(ss, off);

    __shared__ float red[4];
    __shared__ float scale_sh;
    if ((tid & 63) == 0) red[tid >> 6] = ss;
    __syncthreads();
    if (tid == 0) {
        const float tot = red[0] + red[1] + red[2] + red[3];
        scale_sh = rsqrtf(tot * (1.0f/512.0f) + 1e-6f);
    }
    __syncthreads();
    const float sc = scale_sh;
    kvn[(size_t)tok*512 + tid]       = __float2bfloat16(x0 * sc);
    kvn[(size_t)tok*512 + tid + 256] = __float2bfloat16(x1 * sc);

    if (tid < 32) {
        const int t = tok & (T_ - 1);
        const float c = cs[t*32 + tid];
        const float s = sn[t*32 + tid];
        const float xr = __bfloat162float(row[KVR_ + 2*tid]);
        const float xi = __bfloat162float(row[KVR_ + 2*tid + 1]);
        kr[(size_t)tok*64 + 2*tid]     = __float2bfloat16(xr * c - xi * s);
        kr[(size_t)tok*64 + 2*tid + 1] = __float2bfloat16(xr * s + xi * c);
    }
}

// ---------------------------------------------------------------------------
// MFMA flash attention, BQ=256 / BK=64, 8 waves, two q-strips per wave.
// Softmax in base-2 (log2e folded into Q pre-scale; exp2f everywhere).
// Fragment-ordered LDS staging + register-prefetch pipeline (r8/r9).
// ---------------------------------------------------------------------------
__device__ __forceinline__ void attn_stage_regs(
    v8bf* R,
    const __hip_bfloat16* __restrict__ kn,
    const __hip_bfloat16* __restrict__ kr,
    const __hip_bfloat16* __restrict__ vth,
    size_t tokb, int j0, int h, int wv, int ln, int quad)
{
    #pragma unroll
    for (int i = 0; i < 5; ++i) {
        const int f = wv * 5 + i;
        if (f < 24) {
            const int s = f >> 2, t = f & 3;
            const size_t row = tokb + j0 + t*16 + ln;
            R[i] = (s < 4)
                ? *(const v8bf*)(kn + row*2048 + h*128 + s*32 + quad*8)
                : *(const v8bf*)(kr + row*64 + (s-4)*32 + quad*8);
        } else {
            const int g2 = f - 24, nt = g2 >> 1, s2 = g2 & 1;
            R[i] = *(const v8bf*)(vth + (size_t)(nt*16 + ln)*NTOK
                                  + tokb + j0 + s2*32 + quad*8);
        }
    }
}

__global__ __launch_bounds__(512, 2) void attn_mfma(
    const __hip_bfloat16* __restrict__ q,
    const __hip_bfloat16* __restrict__ kn,
    const __hip_bfloat16* __restrict__ kr,
    const __hip_bfloat16* __restrict__ vt,
    const float* __restrict__ cs,
    const float* __restrict__ sn,
    __hip_bfloat16* __restrict__ att)
{
    __shared__ unsigned short KVf[40 * 512];        // 40 KB, fragment-ordered
    __shared__ unsigned short P_s[8][2][16 * 72];   // 36 KB, per-wave/strip P

    const int tid  = threadIdx.x;
    const int lane = tid & 63;
    const int ln   = tid & 15;
    const int quad = (tid >> 4) & 3;
    const int wv   = tid >> 6;                      // 0..7

    const int qt = (int)(gridDim.x - 1) - (int)blockIdx.x;  // longest first
    const int h  = blockIdx.y, b = blockIdx.z;
    const int q0 = qt * 256;
    const size_t tokb = (size_t)b * T_;
    const __hip_bfloat16* vth = vt + (size_t)h * 128 * NTOK;

    // ---- Q fragments for both strips (A layout), fused RoPE + base2 scale ----
    v8bf qf[2][6];
    #pragma unroll
    for (int st = 0; st < 2; ++st) {
        const int trow = q0 + st*128 + wv*16 + ln;
        const __hip_bfloat16* qrow =
            q + (tokb + trow) * (size_t)(H_*QKD_) + h*QKD_;
        #pragma unroll
        for (int s = 0; s < 6; ++s) {
            ushort8_t raw = *(const ushort8_t*)(qrow + s*32 + quad*8);
            ushort8_t o;
            if (s < 4) {
                #pragma unroll
                for (int i = 0; i < 8; ++i)
                    o[i] = f2bf(bf2f(raw[i]) * SCALE2_);
            } else {
                #pragma unroll
                for (int p2 = 0; p2 < 4; ++p2) {
                    const int fi = (s-4)*16 + quad*4 + p2;   // freq index 0..31
                    const float c  = cs[trow*32 + fi];
                    const float sv = sn[trow*32 + fi];
                    const float xr = bf2f(raw[p2*2]);
                    const float xi = bf2f(raw[p2*2+1]);
                    o[p2*2]   = f2bf((xr*c - xi*sv) * SCALE2_);
                    o[p2*2+1] = f2bf((xr*sv + xi*c) * SCALE2_);
                }
            }
            qf[st][s] = __builtin_bit_cast(v8bf, o);
        }
    }

    v4f O[2][8];
    #pragma unroll
    for (int st = 0; st < 2; ++st)
        #pragma unroll
        for (int nt = 0; nt < 8; ++nt) O[st][nt] = (v4f){0.f, 0.f, 0.f, 0.f};
    float m_r[2][4], l_r[2][4];
    #pragma unroll
    for (int st = 0; st < 2; ++st)
        #pragma unroll
        for (int r = 0; r < 4; ++r) { m_r[st][r] = -1e30f; l_r[st][r] = 0.0f; }

    const int qmin0 = q0 + wv*16;
    const int qmin1 = q0 + 128 + wv*16;
    const int nkt = (q0 + 256) >> 6;

    // prefetch tile 0
    v8bf R[5];
    attn_stage_regs(R, kn, kr, vth, tokb, 0, h, wv, ln, quad);

    for (int kt = 0; kt < nkt; ++kt) {
        const int j0 = kt << 6;

        #pragma unroll
        for (int i = 0; i < 5; ++i)
            *(v8bf*)&KVf[(wv*5 + i)*512 + lane*8] = R[i];
        __syncthreads();

        if (kt + 1 < nkt)
            attn_stage_regs(R, kn, kr, vth, tokb, j0 + 64, h, wv, ln, quad);

        const bool act0 = (j0 <= qmin0 + 15);   // wave-uniform
        const bool act1 = (j0 <= qmin1 + 15);

        if (act1) {
            // ---- S = Q K^T ----
            v4f S[2][4];
            #pragma unroll
            for (int st = 0; st < 2; ++st)
                #pragma unroll
                for (int t = 0; t < 4; ++t) S[st][t] = (v4f){0.f, 0.f, 0.f, 0.f};
            if (act0) {
                #pragma unroll
                for (int s = 0; s < 6; ++s)
                    #pragma unroll
                    for (int t = 0; t < 4; ++t) {
                        const v8bf kb = *(const v8bf*)&KVf[(s*4 + t)*512 + lane*8];
                        S[0][t] = __builtin_amdgcn_mfma_f32_16x16x32_bf16(qf[0][s], kb, S[0][t], 0, 0, 0);
                        S[1][t] = __builtin_amdgcn_mfma_f32_16x16x32_bf16(qf[1][s], kb, S[1][t], 0, 0, 0);
                    }
            } else {
                #pragma unroll
                for (int s = 0; s < 6; ++s)
                    #pragma unroll
                    for (int t = 0; t < 4; ++t) {
                        const v8bf kb = *(const v8bf*)&KVf[(s*4 + t)*512 + lane*8];
                        S[1][t] = __builtin_amdgcn_mfma_f32_16x16x32_bf16(qf[1][s], kb, S[1][t], 0, 0, 0);
                    }
            }

            // ---- per-strip mask + online softmax (base-2) + P write ----
            float alpha[2][4];
            #pragma unroll
            for (int st = 0; st < 2; ++st) {
                if (st == 0 && !act0) continue;
                const int qmin = (st == 0) ? qmin0 : qmin1;
                if (j0 + 63 > qmin) {
                    #pragma unroll
                    for (int t = 0; t < 4; ++t) {
                        const int kpos = j0 + t*16 + ln;
                        #pragma unroll
                        for (int r = 0; r < 4; ++r)
                            if (kpos > qmin + quad*4 + r) S[st][t][r] = -1e30f;
                    }
                }
                #pragma unroll
                for (int r = 0; r < 4; ++r) {
                    float mx = fmaxf(fmaxf(S[st][0][r], S[st][1][r]),
                                     fmaxf(S[st][2][r], S[st][3][r]));
                    #pragma unroll
                    for (int off = 1; off < 16; off <<= 1)
                        mx = fmaxf(mx, __shfl_xor(mx, off));
                    const float mn = fmaxf(m_r[st][r], mx);
                    alpha[st][r] = exp2f(m_r[st][r] - mn);
                    m_r[st][r] = mn;
                }
                float rs[4] = {0.f, 0.f, 0.f, 0.f};
                #pragma unroll
                for (int t = 0; t < 4; ++t)
                    #pragma unroll
                    for (int r = 0; r < 4; ++r) {
                        const float pp = exp2f(S[st][t][r] - m_r[st][r]);
                        S[st][t][r] = pp;
                        rs[r] += pp;
                    }
                #pragma unroll
                for (int r = 0; r < 4; ++r) {
                    #pragma unroll
                    for (int off = 1; off < 16; off <<= 1)
                        rs[r] += __shfl_xor(rs[r], off);
                    l_r[st][r] = l_r[st][r]*alpha[st][r] + rs[r];
                }
                #pragma unroll
                for (int t = 0; t < 4; ++t)
                    #pragma unroll
                    for (int r = 0; r < 4; ++r)
                        P_s[wv][st][(quad*4 + r)*72 + t*16 + ln] = f2bf(S[st][t][r]);
                #pragma unroll
                for (int nt = 0; nt < 8; ++nt)
                    #pragma unroll
                    for (int r = 0; r < 4; ++r)
                        O[st][nt][r] *= alpha[st][r];
            }

            // ---- O += P V ----
            #pragma unroll
            for (int s2 = 0; s2 < 2; ++s2) {
                const v8bf pa1 = *(const v8bf*)&P_s[wv][1][ln*72 + s2*32 + quad*8];
                if (act0) {
                    const v8bf pa0 = *(const v8bf*)&P_s[wv][0][ln*72 + s2*32 + quad*8];
                    #pragma unroll
                    for (int nt = 0; nt < 8; ++nt) {
                        const v8bf vb = *(const v8bf*)&KVf[(24 + nt*2 + s2)*512 + lane*8];
                        O[0][nt] = __builtin_amdgcn_mfma_f32_16x16x32_bf16(pa0, vb, O[0][nt], 0, 0, 0);
                        O[1][nt] = __builtin_amdgcn_mfma_f32_16x16x32_bf16(pa1, vb, O[1][nt], 0, 0, 0);
                    }
                } else {
                    #pragma unroll
                    for (int nt = 0; nt < 8; ++nt) {
                        const v8bf vb = *(const v8bf*)&KVf[(24 + nt*2 + s2)*512 + lane*8];
                        O[1][nt] = __builtin_amdgcn_mfma_f32_16x16x32_bf16(pa1, vb, O[1][nt], 0, 0, 0);
                    }
                }
            }
        }
        __syncthreads();
    }

    // ---- epilogue: both strips ----
    #pragma unroll
    for (int st = 0; st < 2; ++st) {
        __hip_bfloat16* obase =
            att + (tokb + q0 + st*128 + wv*16) * (size_t)(H_*VDIM_) + h*VDIM_;
        #pragma unroll
        for (int r = 0; r < 4; ++r) {
            const float inv = 1.0f / l_r[st][r];
            __hip_bfloat16* orow = obase + (size_t)(quad*4 + r) * (H_*VDIM_);
            #pragma unroll
            for (int nt = 0; nt < 8; ++nt)
                orow[nt*16 + ln] = __float2bfloat16(O[st][nt][r] * inv);
        }
    }
}

// Diagnostic fallback
__global__ void fill_zero(float* p, int n) {
    int i = blockIdx.x * 256 + threadIdx.x;
    if (i < n) p[i] = 0.0f;
}

// ---------------------------------------------------------------------------
extern "C" void kernel_launch(void* const* d_in, const int* in_sizes, int n_in,
                              void* d_out, int out_size, void* d_ws, size_t ws_size,
                              hipStream_t stream)
{
    const float* x      = (const float*)d_in[0];
    const float* wq_w   = (const float*)d_in[1];
    const float* wq_b   = (const float*)d_in[2];
    const float* wkva_w = (const float*)d_in[3];
    const float* wkva_b = (const float*)d_in[4];
    const float* wkvb_w = (const float*)d_in[5];
    const float* wkvb_b = (const float*)d_in[6];
    const float* wo_w   = (const float*)d_in[7];
    const float* wo_b   = (const float*)d_in[8];
    const float* cs     = (const float*)d_in[9];
    const float* sn     = (const float*)d_in[10];

    const size_t q_b    = (size_t)NTOK * 3072 * 2;
    const size_t kn_b   = (size_t)NTOK * 2048 * 2;
    const size_t vt_b   = (size_t)H_ * 128 * NTOK * 2;
    const size_t xb_b   = (size_t)NTOK * 1024 * 2;
    const size_t kvap_b = (size_t)NTOK * 640 * 2;
    const size_t kvn_b  = (size_t)NTOK * 512 * 2;
    const size_t wq_b_b = (size_t)3072 * 1024 * 2;
    const size_t wkva_b_b = (size_t)640 * 1024 * 2;
    const size_t wkvb_b_b = (size_t)4096 * 512 * 2;
    const size_t wo_b_b   = (size_t)1024 * 2048 * 2;
    const size_t bias_b   = 4096;
    const size_t need = q_b + kn_b + vt_b + xb_b + kvap_b + kvn_b +
                        wq_b_b + wkva_b_b + wkvb_b_b + wo_b_b + bias_b;

    if (ws_size < need) {
        fill_zero<<<(out_size + 255) / 256, 256, 0, stream>>>((float*)d_out, out_size);
        return;
    }

    char* p = (char*)d_ws;
    __hip_bfloat16* q    = (__hip_bfloat16*)p;             p += q_b;
    __hip_bfloat16* kn   = (__hip_bfloat16*)p;             p += kn_b;
    __hip_bfloat16* vt   = (__hip_bfloat16*)p;             p += vt_b;
    char*           dynr = p;
    __hip_bfloat16* xb   = (__hip_bfloat16*)p;             p += xb_b;
    __hip_bfloat16* kvap = (__hip_bfloat16*)p;             p += kvap_b;
    __hip_bfloat16* kvn  = (__hip_bfloat16*)p;             p += kvn_b;
    __hip_bfloat16* wq_bf = (__hip_bfloat16*)p;
    __hip_bfloat16* kr    = (__hip_bfloat16*)p;            p += wq_b_b;
    __hip_bfloat16* wkva_bf = (__hip_bfloat16*)p;          p += wkva_b_b;
    __hip_bfloat16* wkvb_bf = (__hip_bfloat16*)p;          p += wkvb_b_b;
    __hip_bfloat16* wo_bf   = (__hip_bfloat16*)p;          p += wo_b_b;
    float*          bias_pad = (float*)p;
    __hip_bfloat16* attb = (__hip_bfloat16*)dynr;
    float*          out  = (float*)d_out;

    // 1) all conversions, one launch
    cvt_all<<<CVT_TOTAL / 256, 256, 0, stream>>>(
        x, wq_w, wkvb_w, wo_w, wkva_w, wkva_b,
        xb, wq_bf, wkvb_bf, wo_bf, wkva_bf, bias_pad);

    // 2) fused q-proj + kva-proj (one launch; q-RoPE fused in attn)
    gemm_qkva<<<dim3(29, NTOK/128), 256, 0, stream>>>(
        xb, wq_bf, wq_b, q, wkva_bf, bias_pad, kvap);

    // 3) rmsnorm + rope-k
    rmsnorm_ropek<<<NTOK, 256, 0, stream>>>(kvap, kvn, kr, cs, sn);

    // 4) kv_b -> kn (k_nope) + vt (V transposed, coalesced via LDS bounce)
    gemm_mfma<__hip_bfloat16, 1><<<dim3(4096/128, NTOK/128), 256, 0, stream>>>(
        kvn, 512, wkvb_bf, 512, wkvb_b, kn, 0, 512, vt);

    // 5) attention: BQ=256, 8 waves x 2 strips, base-2 softmax
    attn_mfma<<<dim3(T_/256, H_, B_), 512, 0, stream>>>(q, kn, kr, vt, cs, sn, attb);

    // 6) out = att @ wo^T + b  (8192 x 1024, K=2048)
    gemm_mfma<float, 0><<<dim3(1024/128, NTOK/128), 256, 0, stream>>>(
        attb, 2048, wo_bf, 2048, wo_b, out, 1024, 2048, nullptr);
}

// Round 11
// 687.052 us; speedup vs baseline: 1.0870x; 1.0870x over previous
//
#include <hip/hip_runtime.h>
#include <hip/hip_bf16.h>
#include <cmath>

// Problem constants
#define B_    4
#define T_    2048
#define DIM_  1024
#define H_    16
#define NOPE_ 128
#define ROPE_ 64
#define VDIM_ 128
#define KVR_  512
#define QKD_  192          // NOPE + ROPE
#define NTOK  (B_ * T_)    // 8192

static constexpr float SCALE_  = 0.07216878364870322f;            // 1/sqrt(192)
static constexpr float SCALE2_ = 0.07216878364870322f * 1.4426950408889634f; // fold log2(e): softmax in base-2

typedef __attribute__((ext_vector_type(8))) unsigned short ushort8_t;
typedef __bf16 v8bf __attribute__((ext_vector_type(8)));
typedef float  v4f  __attribute__((ext_vector_type(4)));

__device__ __forceinline__ float bf2f(unsigned short u) {
    return __uint_as_float(((unsigned int)u) << 16);
}
// round-to-nearest-even f32 -> bf16 bits (finite inputs)
__device__ __forceinline__ unsigned short f2bf(float f) {
    unsigned int u = __float_as_uint(f);
    u += 0x7FFFu + ((u >> 16) & 1u);
    return (unsigned short)(u >> 16);
}
__device__ __forceinline__ void store1(float* p, float v)          { *p = v; }
__device__ __forceinline__ void store1(__hip_bfloat16* p, float v) { *p = __float2bfloat16(v); }

// RAW v_exp_f32 (D = 2^S0). r10 lesson: exp2f() lowers to the precise OCML
// routine (~6 VALU + branches); this builtin is 1 instruction.
__device__ __forceinline__ float exp2_hw(float x) {
    return __builtin_amdgcn_exp2f(x);
}

// async global->LDS, 16B per lane. LDS dest = wave-uniform base + lane*16.
__device__ __forceinline__ void load_lds16(const void* g, void* l) {
    __builtin_amdgcn_global_load_lds(
        (const __attribute__((address_space(1))) void*)g,
        (__attribute__((address_space(3))) void*)l, 16, 0, 0);
}

__device__ __forceinline__ void cvt4(const float* s, __hip_bfloat16* d, int q4) {
    const int i = q4 * 4;
    const float4 v = *(const float4*)(s + i);
    ushort4 o;
    o.x = f2bf(v.x); o.y = f2bf(v.y); o.z = f2bf(v.z); o.w = f2bf(v.w);
    *(ushort4*)((unsigned short*)d + i) = o;
}

// ---------------------------------------------------------------------------
// ONE kernel for all fp32->bf16 conversions.
// ---------------------------------------------------------------------------
#define X4_   (NTOK*1024/4)     // 2,097,152
#define Q4_   (3072*1024/4)     //   786,432
#define KB4_  (4096*512/4)      //   524,288
#define O4_   (1024*2048/4)     //   524,288
#define A4_   (640*1024/4)      //   163,840
#define CVT_TOTAL (X4_ + Q4_ + KB4_ + O4_ + A4_)   // 4,096,000 -> 16,000 blocks

__global__ __launch_bounds__(256) void cvt_all(
    const float* __restrict__ x,    const float* __restrict__ wq,
    const float* __restrict__ wkvb, const float* __restrict__ wo,
    const float* __restrict__ wkva, const float* __restrict__ wkva_bias,
    __hip_bfloat16* __restrict__ xb,    __hip_bfloat16* __restrict__ wqb,
    __hip_bfloat16* __restrict__ wkvbb, __hip_bfloat16* __restrict__ wob,
    __hip_bfloat16* __restrict__ wkvab, float* __restrict__ bias_pad)
{
    int idx = blockIdx.x * 256 + threadIdx.x;
    if (idx < X4_) { cvt4(x, xb, idx); return; }
    idx -= X4_;
    if (idx < Q4_) { cvt4(wq, wqb, idx); return; }
    idx -= Q4_;
    if (idx < KB4_) { cvt4(wkvb, wkvbb, idx); return; }
    idx -= KB4_;
    if (idx < O4_) { cvt4(wo, wob, idx); return; }
    idx -= O4_;
    if (idx < A4_) {
        const int i = idx * 4;
        ushort4 o;
        if (i < 576 * 1024) {
            const float4 v = *(const float4*)(wkva + i);
            o.x = f2bf(v.x); o.y = f2bf(v.y); o.z = f2bf(v.z); o.w = f2bf(v.w);
        } else {
            o.x = o.y = o.z = o.w = 0;
        }
        *(ushort4*)((unsigned short*)wkvab + i) = o;
        if (idx < 640) bias_pad[idx] = (idx < 576) ? wkva_bias[idx] : 0.0f;
    }
}

// ---------------------------------------------------------------------------
// MFMA GEMM: C[m][n] = sum_k A[m][k]*W[n][k] + bias[n]. A,W bf16, acc fp32.
// Tiles 128x128xBK32, 4 waves (2x2 of 64x64), 16x16x32 MFMA.
// EPI=0: plain store to C.
// EPI=1: kv_b split epilogue: even 128-tiles -> kn; odd tiles -> vt via an
//        LDS-bounce transpose (XOR-swizzled) -> coalesced 256B vt rows.
// ---------------------------------------------------------------------------
template <typename CT, int EPI>
__global__ __launch_bounds__(256) void gemm_mfma(
    const __hip_bfloat16* __restrict__ A, int lda,
    const __hip_bfloat16* __restrict__ W, int ldw,
    const float* __restrict__ bias,
    CT* __restrict__ C, int ldc, int K,
    __hip_bfloat16* __restrict__ vt)
{
    __shared__ unsigned short smem[2 * 128 * 32];   // A tile | B tile (16 KB)
    unsigned short* A_s = smem;
    unsigned short* B_s = smem + 128 * 32;

    const int tid  = threadIdx.x;
    const int ln   = tid & 63;
    const int wv   = tid >> 6;
    const int l15  = ln & 15;
    const int quad = ln >> 4;
    const int wm   = wv & 1, wn = wv >> 1;
    const int n0 = blockIdx.x * 128, m0 = blockIdx.y * 128;

    v4f acc[4][4] = {};

    for (int k0 = 0; k0 < K; k0 += 32) {
        __syncthreads();
        #pragma unroll
        for (int it = 0; it < 2; ++it) {
            const int idx = it * 256 + wv * 64;   // wave-uniform LDS slot base
            const int li  = idx + ln;
            const int row = li >> 2, ch = li & 3;
            load_lds16(A + (size_t)(m0 + row) * lda + k0 + ch * 8, &A_s[idx * 8]);
            load_lds16(W + (size_t)(n0 + row) * ldw + k0 + ch * 8, &B_s[idx * 8]);
        }
        __syncthreads();

        v8bf af[4], bf_[4];
        #pragma unroll
        for (int i = 0; i < 4; ++i) {
            af[i]  = *(const v8bf*)&A_s[(wm * 64 + i * 16 + l15) * 32 + quad * 8];
            bf_[i] = *(const v8bf*)&B_s[(wn * 64 + i * 16 + l15) * 32 + quad * 8];
        }
        #pragma unroll
        for (int i = 0; i < 4; ++i)
            #pragma unroll
            for (int j = 0; j < 4; ++j)
                acc[i][j] = __builtin_amdgcn_mfma_f32_16x16x32_bf16(
                                af[i], bf_[j], acc[i][j], 0, 0, 0);
    }

    if (EPI == 0) {
        #pragma unroll
        for (int i = 0; i < 4; ++i) {
            const int mrow = m0 + wm * 64 + i * 16 + quad * 4;
            #pragma unroll
            for (int j = 0; j < 4; ++j) {
                const int ncol = n0 + wn * 64 + j * 16 + l15;
                const float bb = bias[ncol];
                #pragma unroll
                for (int r = 0; r < 4; ++r)
                    store1(C + (size_t)(mrow + r) * ldc + ncol, acc[i][j][r] + bb);
            }
        }
    } else {
        const int head = n0 >> 8;
        const bool is_v = (n0 & 128) != 0;
        if (!is_v) {
            #pragma unroll
            for (int i = 0; i < 4; ++i) {
                const int mrow = m0 + wm * 64 + i * 16 + quad * 4;
                #pragma unroll
                for (int j = 0; j < 4; ++j) {
                    const int ncl = wn * 64 + j * 16 + l15;
                    const float bb = bias[n0 + ncl];
                    __hip_bfloat16* kn = (__hip_bfloat16*)C;
                    #pragma unroll
                    for (int r = 0; r < 4; ++r)
                        kn[(size_t)(mrow + r) * 2048 + head * 128 + ncl] =
                            __float2bfloat16(acc[i][j][r] + bb);
                }
            }
        } else {
            // V tile: transpose via LDS in two 64-row passes, coalesced stores.
            __syncthreads();   // all waves finished reading A_s/B_s
            #pragma unroll
            for (int p = 0; p < 2; ++p) {
                if (p) __syncthreads();    // pass-0 stores done before overwrite
                if (wn == p) {
                    #pragma unroll
                    for (int i = 0; i < 4; ++i) {
                        #pragma unroll
                        for (int j = 0; j < 4; ++j) {
                            const int nl = j * 16 + l15;       // 0..63 in half
                            const float bb = bias[n0 + p*64 + nl];
                            const int ml = wm * 64 + i * 16 + quad * 4;
                            // XOR swizzle at 8-ushort granularity (2-way banks)
                            const int seg = (ml >> 3) ^ (nl & 15);
                            ushort4 pk;
                            pk.x = f2bf(acc[i][j][0] + bb);
                            pk.y = f2bf(acc[i][j][1] + bb);
                            pk.z = f2bf(acc[i][j][2] + bb);
                            pk.w = f2bf(acc[i][j][3] + bb);
                            *(ushort4*)&smem[nl * 128 + seg * 8 + (ml & 7)] = pk;
                        }
                    }
                }
                __syncthreads();
                // store 64 rows (vd) x 128 toks, 256B per row, unswizzle read
                #pragma unroll
                for (int it = 0; it < 4; ++it) {
                    const int flat = tid + it * 256;
                    const int row = flat >> 4, seg = flat & 15;
                    const int vd = head * 128 + p * 64 + row;
                    *(ushort8_t*)((unsigned short*)vt + (size_t)vd * NTOK + m0 + seg * 8)
                        = *(const ushort8_t*)&smem[row * 128 + (seg ^ (row & 15)) * 8];
                }
            }
        }
    }
}

// ---------------------------------------------------------------------------
// Fused q-proj + kva-proj (same A operand, K=1024): one launch, branch on bx.
// ---------------------------------------------------------------------------
__global__ __launch_bounds__(256) void gemm_qkva(
    const __hip_bfloat16* __restrict__ A,
    const __hip_bfloat16* __restrict__ Wq, const float* __restrict__ biasq,
    __hip_bfloat16* __restrict__ Cq,
    const __hip_bfloat16* __restrict__ Wa, const float* __restrict__ biasa,
    __hip_bfloat16* __restrict__ Ca)
{
    __shared__ unsigned short smem[2 * 128 * 32];
    unsigned short* A_s = smem;
    unsigned short* B_s = smem + 128 * 32;

    const bool is_q = blockIdx.x < 24;
    const __hip_bfloat16* W = is_q ? Wq : Wa;
    const float* bias       = is_q ? biasq : biasa;
    __hip_bfloat16* C       = is_q ? Cq : Ca;
    const int ldc = is_q ? 3072 : 640;
    const int n0  = (is_q ? blockIdx.x : (blockIdx.x - 24)) * 128;
    const int m0  = blockIdx.y * 128;

    const int tid  = threadIdx.x;
    const int ln   = tid & 63;
    const int wv   = tid >> 6;
    const int l15  = ln & 15;
    const int quad = ln >> 4;
    const int wm   = wv & 1, wn = wv >> 1;

    v4f acc[4][4] = {};

    for (int k0 = 0; k0 < 1024; k0 += 32) {
        __syncthreads();
        #pragma unroll
        for (int it = 0; it < 2; ++it) {
            const int idx = it * 256 + wv * 64;
            const int li  = idx + ln;
            const int row = li >> 2, ch = li & 3;
            load_lds16(A + (size_t)(m0 + row) * 1024 + k0 + ch * 8, &A_s[idx * 8]);
            load_lds16(W + (size_t)(n0 + row) * 1024 + k0 + ch * 8, &B_s[idx * 8]);
        }
        __syncthreads();

        v8bf af[4], bf_[4];
        #pragma unroll
        for (int i = 0; i < 4; ++i) {
            af[i]  = *(const v8bf*)&A_s[(wm * 64 + i * 16 + l15) * 32 + quad * 8];
            bf_[i] = *(const v8bf*)&B_s[(wn * 64 + i * 16 + l15) * 32 + quad * 8];
        }
        #pragma unroll
        for (int i = 0; i < 4; ++i)
            #pragma unroll
            for (int j = 0; j < 4; ++j)
                acc[i][j] = __builtin_amdgcn_mfma_f32_16x16x32_bf16(
                                af[i], bf_[j], acc[i][j], 0, 0, 0);
    }

    #pragma unroll
    for (int i = 0; i < 4; ++i) {
        const int mrow = m0 + wm * 64 + i * 16 + quad * 4;
        #pragma unroll
        for (int j = 0; j < 4; ++j) {
            const int ncol = n0 + wn * 64 + j * 16 + l15;
            const float bb = bias[ncol];
            #pragma unroll
            for (int r = 0; r < 4; ++r)
                C[(size_t)(mrow + r) * ldc + ncol] = __float2bfloat16(acc[i][j][r] + bb);
        }
    }
}

// ---------------------------------------------------------------------------
// RMS-norm kv_a[:,0:512] -> kvn bf16; RoPE kv_a[:,512:576] -> kr bf16.
// ---------------------------------------------------------------------------
__global__ __launch_bounds__(256) void rmsnorm_ropek(
    const __hip_bfloat16* __restrict__ kva,
    __hip_bfloat16* __restrict__ kvn,
    __hip_bfloat16* __restrict__ kr,
    const float* __restrict__ cs,
    const float* __restrict__ sn)
{
    const int tok = blockIdx.x;
    const int tid = threadIdx.x;
    const __hip_bfloat16* row = kva + (size_t)tok * 640;

    const float x0 = __bfloat162float(row[tid]);
    const float x1 = __bfloat162float(row[tid + 256]);
    float ss = x0*x0 + x1*x1;
    #pragma unroll
    for (int off = 32; off >= 1; off >>= 1)
        ss += __shfl_down(ss, off);

    __shared__ float red[4];
    __shared__ float scale_sh;
    if ((tid & 63) == 0) red[tid >> 6] = ss;
    __syncthreads();
    if (tid == 0) {
        const float tot = red[0] + red[1] + red[2] + red[3];
        scale_sh = rsqrtf(tot * (1.0f/512.0f) + 1e-6f);
    }
    __syncthreads();
    const float sc = scale_sh;
    kvn[(size_t)tok*512 + tid]       = __float2bfloat16(x0 * sc);
    kvn[(size_t)tok*512 + tid + 256] = __float2bfloat16(x1 * sc);

    if (tid < 32) {
        const int t = tok & (T_ - 1);
        const float c = cs[t*32 + tid];
        const float s = sn[t*32 + tid];
        const float xr = __bfloat162float(row[KVR_ + 2*tid]);
        const float xi = __bfloat162float(row[KVR_ + 2*tid + 1]);
        kr[(size_t)tok*64 + 2*tid]     = __float2bfloat16(xr * c - xi * s);
        kr[(size_t)tok*64 + 2*tid + 1] = __float2bfloat16(xr * s + xi * c);
    }
}

// ---------------------------------------------------------------------------
// MFMA flash attention, BQ=256 / BK=64, 8 waves, two q-strips per wave.
// Softmax in base-2 via raw v_exp_f32 (log2e folded into Q pre-scale).
// Fragment-ordered LDS staging + register-prefetch pipeline.
// ---------------------------------------------------------------------------
__device__ __forceinline__ void attn_stage_regs(
    v8bf* R,
    const __hip_bfloat16* __restrict__ kn,
    const __hip_bfloat16* __restrict__ kr,
    const __hip_bfloat16* __restrict__ vth,
    size_t tokb, int j0, int h, int wv, int ln, int quad)
{
    #pragma unroll
    for (int i = 0; i < 5; ++i) {
        const int f = wv * 5 + i;
        if (f < 24) {
            const int s = f >> 2, t = f & 3;
            const size_t row = tokb + j0 + t*16 + ln;
            R[i] = (s < 4)
                ? *(const v8bf*)(kn + row*2048 + h*128 + s*32 + quad*8)
                : *(const v8bf*)(kr + row*64 + (s-4)*32 + quad*8);
        } else {
            const int g2 = f - 24, nt = g2 >> 1, s2 = g2 & 1;
            R[i] = *(const v8bf*)(vth + (size_t)(nt*16 + ln)*NTOK
                                  + tokb + j0 + s2*32 + quad*8);
        }
    }
}

__global__ __launch_bounds__(512, 2) void attn_mfma(
    const __hip_bfloat16* __restrict__ q,
    const __hip_bfloat16* __restrict__ kn,
    const __hip_bfloat16* __restrict__ kr,
    const __hip_bfloat16* __restrict__ vt,
    const float* __restrict__ cs,
    const float* __restrict__ sn,
    __hip_bfloat16* __restrict__ att)
{
    __shared__ unsigned short KVf[40 * 512];        // 40 KB, fragment-ordered
    __shared__ unsigned short P_s[8][2][16 * 72];   // 36 KB, per-wave/strip P

    const int tid  = threadIdx.x;
    const int lane = tid & 63;
    const int ln   = tid & 15;
    const int quad = (tid >> 4) & 3;
    const int wv   = tid >> 6;                      // 0..7

    const int qt = (int)(gridDim.x - 1) - (int)blockIdx.x;  // longest first
    const int h  = blockIdx.y, b = blockIdx.z;
    const int q0 = qt * 256;
    const size_t tokb = (size_t)b * T_;
    const __hip_bfloat16* vth = vt + (size_t)h * 128 * NTOK;

    // ---- Q fragments for both strips (A layout), fused RoPE + base2 scale ----
    v8bf qf[2][6];
    #pragma unroll
    for (int st = 0; st < 2; ++st) {
        const int trow = q0 + st*128 + wv*16 + ln;
        const __hip_bfloat16* qrow =
            q + (tokb + trow) * (size_t)(H_*QKD_) + h*QKD_;
        #pragma unroll
        for (int s = 0; s < 6; ++s) {
            ushort8_t raw = *(const ushort8_t*)(qrow + s*32 + quad*8);
            ushort8_t o;
            if (s < 4) {
                #pragma unroll
                for (int i = 0; i < 8; ++i)
                    o[i] = f2bf(bf2f(raw[i]) * SCALE2_);
            } else {
                #pragma unroll
                for (int p2 = 0; p2 < 4; ++p2) {
                    const int fi = (s-4)*16 + quad*4 + p2;   // freq index 0..31
                    const float c  = cs[trow*32 + fi];
                    const float sv = sn[trow*32 + fi];
                    const float xr = bf2f(raw[p2*2]);
                    const float xi = bf2f(raw[p2*2+1]);
                    o[p2*2]   = f2bf((xr*c - xi*sv) * SCALE2_);
                    o[p2*2+1] = f2bf((xr*sv + xi*c) * SCALE2_);
                }
            }
            qf[st][s] = __builtin_bit_cast(v8bf, o);
        }
    }

    v4f O[2][8];
    #pragma unroll
    for (int st = 0; st < 2; ++st)
        #pragma unroll
        for (int nt = 0; nt < 8; ++nt) O[st][nt] = (v4f){0.f, 0.f, 0.f, 0.f};
    float m_r[2][4], l_r[2][4];
    #pragma unroll
    for (int st = 0; st < 2; ++st)
        #pragma unroll
        for (int r = 0; r < 4; ++r) { m_r[st][r] = -1e30f; l_r[st][r] = 0.0f; }

    const int qmin0 = q0 + wv*16;
    const int qmin1 = q0 + 128 + wv*16;
    const int nkt = (q0 + 256) >> 6;

    // prefetch tile 0
    v8bf R[5];
    attn_stage_regs(R, kn, kr, vth, tokb, 0, h, wv, ln, quad);

    for (int kt = 0; kt < nkt; ++kt) {
        const int j0 = kt << 6;

        #pragma unroll
        for (int i = 0; i < 5; ++i)
            *(v8bf*)&KVf[(wv*5 + i)*512 + lane*8] = R[i];
        __syncthreads();

        if (kt + 1 < nkt)
            attn_stage_regs(R, kn, kr, vth, tokb, j0 + 64, h, wv, ln, quad);

        const bool act0 = (j0 <= qmin0 + 15);   // wave-uniform
        const bool act1 = (j0 <= qmin1 + 15);

        if (act1) {
            // ---- S = Q K^T ----
            v4f S[2][4];
            #pragma unroll
            for (int st = 0; st < 2; ++st)
                #pragma unroll
                for (int t = 0; t < 4; ++t) S[st][t] = (v4f){0.f, 0.f, 0.f, 0.f};
            if (act0) {
                #pragma unroll
                for (int s = 0; s < 6; ++s)
                    #pragma unroll
                    for (int t = 0; t < 4; ++t) {
                        const v8bf kb = *(const v8bf*)&KVf[(s*4 + t)*512 + lane*8];
                        S[0][t] = __builtin_amdgcn_mfma_f32_16x16x32_bf16(qf[0][s], kb, S[0][t], 0, 0, 0);
                        S[1][t] = __builtin_amdgcn_mfma_f32_16x16x32_bf16(qf[1][s], kb, S[1][t], 0, 0, 0);
                    }
            } else {
                #pragma unroll
                for (int s = 0; s < 6; ++s)
                    #pragma unroll
                    for (int t = 0; t < 4; ++t) {
                        const v8bf kb = *(const v8bf*)&KVf[(s*4 + t)*512 + lane*8];
                        S[1][t] = __builtin_amdgcn_mfma_f32_16x16x32_bf16(qf[1][s], kb, S[1][t], 0, 0, 0);
                    }
            }

            // ---- per-strip mask + online softmax (base-2, hw exp) + P write ----
            float alpha[2][4];
            #pragma unroll
            for (int st = 0; st < 2; ++st) {
                if (st == 0 && !act0) continue;
                const int qmin = (st == 0) ? qmin0 : qmin1;
                if (j0 + 63 > qmin) {
                    #pragma unroll
                    for (int t = 0; t < 4; ++t) {
                        const int kpos = j0 + t*16 + ln;
                        #pragma unroll
                        for (int r = 0; r < 4; ++r)
                            if (kpos > qmin + quad*4 + r) S[st][t][r] = -1e30f;
                    }
                }
                #pragma unroll
                for (int r = 0; r < 4; ++r) {
                    float mx = fmaxf(fmaxf(S[st][0][r], S[st][1][r]),
                                     fmaxf(S[st][2][r], S[st][3][r]));
                    #pragma unroll
                    for (int off = 1; off < 16; off <<= 1)
                        mx = fmaxf(mx, __shfl_xor(mx, off));
                    const float mn = fmaxf(m_r[st][r], mx);
                    alpha[st][r] = exp2_hw(m_r[st][r] - mn);
                    m_r[st][r] = mn;
                }
                float rs[4] = {0.f, 0.f, 0.f, 0.f};
                #pragma unroll
                for (int t = 0; t < 4; ++t)
                    #pragma unroll
                    for (int r = 0; r < 4; ++r) {
                        const float pp = exp2_hw(S[st][t][r] - m_r[st][r]);
                        S[st][t][r] = pp;
                        rs[r] += pp;
                    }
                #pragma unroll
                for (int r = 0; r < 4; ++r) {
                    #pragma unroll
                    for (int off = 1; off < 16; off <<= 1)
                        rs[r] += __shfl_xor(rs[r], off);
                    l_r[st][r] = l_r[st][r]*alpha[st][r] + rs[r];
                }
                #pragma unroll
                for (int t = 0; t < 4; ++t)
                    #pragma unroll
                    for (int r = 0; r < 4; ++r)
                        P_s[wv][st][(quad*4 + r)*72 + t*16 + ln] = f2bf(S[st][t][r]);
                #pragma unroll
                for (int nt = 0; nt < 8; ++nt)
                    #pragma unroll
                    for (int r = 0; r < 4; ++r)
                        O[st][nt][r] *= alpha[st][r];
            }

            // ---- O += P V ----
            #pragma unroll
            for (int s2 = 0; s2 < 2; ++s2) {
                const v8bf pa1 = *(const v8bf*)&P_s[wv][1][ln*72 + s2*32 + quad*8];
                if (act0) {
                    const v8bf pa0 = *(const v8bf*)&P_s[wv][0][ln*72 + s2*32 + quad*8];
                    #pragma unroll
                    for (int nt = 0; nt < 8; ++nt) {
                        const v8bf vb = *(const v8bf*)&KVf[(24 + nt*2 + s2)*512 + lane*8];
                        O[0][nt] = __builtin_amdgcn_mfma_f32_16x16x32_bf16(pa0, vb, O[0][nt], 0, 0, 0);
                        O[1][nt] = __builtin_amdgcn_mfma_f32_16x16x32_bf16(pa1, vb, O[1][nt], 0, 0, 0);
                    }
                } else {
                    #pragma unroll
                    for (int nt = 0; nt < 8; ++nt) {
                        const v8bf vb = *(const v8bf*)&KVf[(24 + nt*2 + s2)*512 + lane*8];
                        O[1][nt] = __builtin_amdgcn_mfma_f32_16x16x32_bf16(pa1, vb, O[1][nt], 0, 0, 0);
                    }
                }
            }
        }
        __syncthreads();
    }

    // ---- epilogue: both strips ----
    #pragma unroll
    for (int st = 0; st < 2; ++st) {
        __hip_bfloat16* obase =
            att + (tokb + q0 + st*128 + wv*16) * (size_t)(H_*VDIM_) + h*VDIM_;
        #pragma unroll
        for (int r = 0; r < 4; ++r) {
            const float inv = 1.0f / l_r[st][r];
            __hip_bfloat16* orow = obase + (size_t)(quad*4 + r) * (H_*VDIM_);
            #pragma unroll
            for (int nt = 0; nt < 8; ++nt)
                orow[nt*16 + ln] = __float2bfloat16(O[st][nt][r] * inv);
        }
    }
}

// Diagnostic fallback
__global__ void fill_zero(float* p, int n) {
    int i = blockIdx.x * 256 + threadIdx.x;
    if (i < n) p[i] = 0.0f;
}

// ---------------------------------------------------------------------------
extern "C" void kernel_launch(void* const* d_in, const int* in_sizes, int n_in,
                              void* d_out, int out_size, void* d_ws, size_t ws_size,
                              hipStream_t stream)
{
    const float* x      = (const float*)d_in[0];
    const float* wq_w   = (const float*)d_in[1];
    const float* wq_b   = (const float*)d_in[2];
    const float* wkva_w = (const float*)d_in[3];
    const float* wkva_b = (const float*)d_in[4];
    const float* wkvb_w = (const float*)d_in[5];
    const float* wkvb_b = (const float*)d_in[6];
    const float* wo_w   = (const float*)d_in[7];
    const float* wo_b   = (const float*)d_in[8];
    const float* cs     = (const float*)d_in[9];
    const float* sn     = (const float*)d_in[10];

    const size_t q_b    = (size_t)NTOK * 3072 * 2;
    const size_t kn_b   = (size_t)NTOK * 2048 * 2;
    const size_t vt_b   = (size_t)H_ * 128 * NTOK * 2;
    const size_t xb_b   = (size_t)NTOK * 1024 * 2;
    const size_t kvap_b = (size_t)NTOK * 640 * 2;
    const size_t kvn_b  = (size_t)NTOK * 512 * 2;
    const size_t wq_b_b = (size_t)3072 * 1024 * 2;
    const size_t wkva_b_b = (size_t)640 * 1024 * 2;
    const size_t wkvb_b_b = (size_t)4096 * 512 * 2;
    const size_t wo_b_b   = (size_t)1024 * 2048 * 2;
    const size_t bias_b   = 4096;
    const size_t need = q_b + kn_b + vt_b + xb_b + kvap_b + kvn_b +
                        wq_b_b + wkva_b_b + wkvb_b_b + wo_b_b + bias_b;

    if (ws_size < need) {
        fill_zero<<<(out_size + 255) / 256, 256, 0, stream>>>((float*)d_out, out_size);
        return;
    }

    char* p = (char*)d_ws;
    __hip_bfloat16* q    = (__hip_bfloat16*)p;             p += q_b;
    __hip_bfloat16* kn   = (__hip_bfloat16*)p;             p += kn_b;
    __hip_bfloat16* vt   = (__hip_bfloat16*)p;             p += vt_b;
    char*           dynr = p;
    __hip_bfloat16* xb   = (__hip_bfloat16*)p;             p += xb_b;
    __hip_bfloat16* kvap = (__hip_bfloat16*)p;             p += kvap_b;
    __hip_bfloat16* kvn  = (__hip_bfloat16*)p;             p += kvn_b;
    __hip_bfloat16* wq_bf = (__hip_bfloat16*)p;
    __hip_bfloat16* kr    = (__hip_bfloat16*)p;            p += wq_b_b;
    __hip_bfloat16* wkva_bf = (__hip_bfloat16*)p;          p += wkva_b_b;
    __hip_bfloat16* wkvb_bf = (__hip_bfloat16*)p;          p += wkvb_b_b;
    __hip_bfloat16* wo_bf   = (__hip_bfloat16*)p;          p += wo_b_b;
    float*          bias_pad = (float*)p;
    __hip_bfloat16* attb = (__hip_bfloat16*)dynr;
    float*          out  = (float*)d_out;

    // 1) all conversions, one launch
    cvt_all<<<CVT_TOTAL / 256, 256, 0, stream>>>(
        x, wq_w, wkvb_w, wo_w, wkva_w, wkva_b,
        xb, wq_bf, wkvb_bf, wo_bf, wkva_bf, bias_pad);

    // 2) fused q-proj + kva-proj (one launch; q-RoPE fused in attn)
    gemm_qkva<<<dim3(29, NTOK/128), 256, 0, stream>>>(
        xb, wq_bf, wq_b, q, wkva_bf, bias_pad, kvap);

    // 3) rmsnorm + rope-k
    rmsnorm_ropek<<<NTOK, 256, 0, stream>>>(kvap, kvn, kr, cs, sn);

    // 4) kv_b -> kn (k_nope) + vt (V transposed, coalesced via LDS bounce)
    gemm_mfma<__hip_bfloat16, 1><<<dim3(4096/128, NTOK/128), 256, 0, stream>>>(
        kvn, 512, wkvb_bf, 512, wkvb_b, kn, 0, 512, vt);

    // 5) attention: BQ=256, 8 waves x 2 strips, base-2 softmax (hw exp)
    attn_mfma<<<dim3(T_/256, H_, B_), 512, 0, stream>>>(q, kn, kr, vt, cs, sn, attb);

    // 6) out = att @ wo^T + b  (8192 x 1024, K=2048)
    gemm_mfma<float, 0><<<dim3(1024/128, NTOK/128), 256, 0, stream>>>(
        attb, 2048, wo_bf, 2048, wo_b, out, 1024, 2048, nullptr);
}

// Round 12
// 634.027 us; speedup vs baseline: 1.1780x; 1.0836x over previous
//
#include <hip/hip_runtime.h>
#include <hip/hip_bf16.h>
#include <cmath>

// Problem constants
#define B_    4
#define T_    2048
#define DIM_  1024
#define H_    16
#define NOPE_ 128
#define ROPE_ 64
#define VDIM_ 128
#define KVR_  512
#define QKD_  192          // NOPE + ROPE
#define NTOK  (B_ * T_)    // 8192

static constexpr float SCALE2_ = 0.07216878364870322f * 1.4426950408889634f; // 1/sqrt(192) * log2(e)

typedef __attribute__((ext_vector_type(8))) unsigned short ushort8_t;
typedef __bf16 v8bf __attribute__((ext_vector_type(8)));
typedef float  v4f  __attribute__((ext_vector_type(4)));

__device__ __forceinline__ float bf2f(unsigned short u) {
    return __uint_as_float(((unsigned int)u) << 16);
}
__device__ __forceinline__ unsigned short f2bf(float f) {
    unsigned int u = __float_as_uint(f);
    u += 0x7FFFu + ((u >> 16) & 1u);
    return (unsigned short)(u >> 16);
}
__device__ __forceinline__ void store1(float* p, float v)          { *p = v; }
__device__ __forceinline__ void store1(__hip_bfloat16* p, float v) { *p = __float2bfloat16(v); }

// RAW v_exp_f32 (D = 2^S0) — 1 instruction (r10 lesson: exp2f is OCML, slow).
__device__ __forceinline__ float exp2_hw(float x) {
    return __builtin_amdgcn_exp2f(x);
}

// async global->LDS, 16B per lane. LDS dest = wave-uniform base + lane*16.
__device__ __forceinline__ void load_lds16(const void* g, void* l) {
    __builtin_amdgcn_global_load_lds(
        (const __attribute__((address_space(1))) void*)g,
        (__attribute__((address_space(3))) void*)l, 16, 0, 0);
}

__device__ __forceinline__ void cvt4(const float* s, __hip_bfloat16* d, int q4) {
    const int i = q4 * 4;
    const float4 v = *(const float4*)(s + i);
    ushort4 o;
    o.x = f2bf(v.x); o.y = f2bf(v.y); o.z = f2bf(v.z); o.w = f2bf(v.w);
    *(ushort4*)((unsigned short*)d + i) = o;
}

// ---------------------------------------------------------------------------
// ONE kernel for all fp32->bf16 conversions.
// ---------------------------------------------------------------------------
#define X4_   (NTOK*1024/4)
#define Q4_   (3072*1024/4)
#define KB4_  (4096*512/4)
#define O4_   (1024*2048/4)
#define A4_   (640*1024/4)
#define CVT_TOTAL (X4_ + Q4_ + KB4_ + O4_ + A4_)

__global__ __launch_bounds__(256) void cvt_all(
    const float* __restrict__ x,    const float* __restrict__ wq,
    const float* __restrict__ wkvb, const float* __restrict__ wo,
    const float* __restrict__ wkva, const float* __restrict__ wkva_bias,
    __hip_bfloat16* __restrict__ xb,    __hip_bfloat16* __restrict__ wqb,
    __hip_bfloat16* __restrict__ wkvbb, __hip_bfloat16* __restrict__ wob,
    __hip_bfloat16* __restrict__ wkvab, float* __restrict__ bias_pad)
{
    int idx = blockIdx.x * 256 + threadIdx.x;
    if (idx < X4_) { cvt4(x, xb, idx); return; }
    idx -= X4_;
    if (idx < Q4_) { cvt4(wq, wqb, idx); return; }
    idx -= Q4_;
    if (idx < KB4_) { cvt4(wkvb, wkvbb, idx); return; }
    idx -= KB4_;
    if (idx < O4_) { cvt4(wo, wob, idx); return; }
    idx -= O4_;
    if (idx < A4_) {
        const int i = idx * 4;
        ushort4 o;
        if (i < 576 * 1024) {
            const float4 v = *(const float4*)(wkva + i);
            o.x = f2bf(v.x); o.y = f2bf(v.y); o.z = f2bf(v.z); o.w = f2bf(v.w);
        } else {
            o.x = o.y = o.z = o.w = 0;
        }
        *(ushort4*)((unsigned short*)wkvab + i) = o;
        if (idx < 640) bias_pad[idx] = (idx < 576) ? wkva_bias[idx] : 0.0f;
    }
}

// ---------------------------------------------------------------------------
// MFMA GEMM: C[m][n] = sum_k A[m][k]*W[n][k] + bias[n].
// EPI=0: plain store to C.
// EPI=1 (kv_b): write FRAGMENT-ORDERED kvf via LDS bounce.
//   kvf layout: [GT=tok/64][h][32 frags][512 ushorts]; frags 0..15 = K_nope
//   (f = s*4 + t; elem (lnf=tok%16, qf=(d>>3)&3, e=d&7), s=d>>5, t=(tok%64)>>4),
//   frags 16..31 = V (f = 16 + nt*2 + s2; nt=vd>>4, s2=(tok%64)>>5,
//   elem (lnv=vd&15, qv=((tok%64)>>3)&3, ev=tok&7)).
//   Each fragment is read by attention at base + lane*16B -> fully coalesced.
// ---------------------------------------------------------------------------
template <typename CT, int EPI>
__global__ __launch_bounds__(256) void gemm_mfma(
    const __hip_bfloat16* __restrict__ A, int lda,
    const __hip_bfloat16* __restrict__ W, int ldw,
    const float* __restrict__ bias,
    CT* __restrict__ C, int ldc, int K,
    unsigned short* __restrict__ kvf)
{
    __shared__ unsigned short smem[2 * 128 * 32];   // 16 KB: A|B tiles, then frag block
    unsigned short* A_s = smem;
    unsigned short* B_s = smem + 128 * 32;

    const int tid  = threadIdx.x;
    const int ln   = tid & 63;
    const int wv   = tid >> 6;
    const int l15  = ln & 15;
    const int quad = ln >> 4;
    const int wm   = wv & 1, wn = wv >> 1;
    const int n0 = blockIdx.x * 128, m0 = blockIdx.y * 128;

    v4f acc[4][4] = {};

    for (int k0 = 0; k0 < K; k0 += 32) {
        __syncthreads();
        #pragma unroll
        for (int it = 0; it < 2; ++it) {
            const int idx = it * 256 + wv * 64;
            const int li  = idx + ln;
            const int row = li >> 2, ch = li & 3;
            load_lds16(A + (size_t)(m0 + row) * lda + k0 + ch * 8, &A_s[idx * 8]);
            load_lds16(W + (size_t)(n0 + row) * ldw + k0 + ch * 8, &B_s[idx * 8]);
        }
        __syncthreads();

        v8bf af[4], bf_[4];
        #pragma unroll
        for (int i = 0; i < 4; ++i) {
            af[i]  = *(const v8bf*)&A_s[(wm * 64 + i * 16 + l15) * 32 + quad * 8];
            bf_[i] = *(const v8bf*)&B_s[(wn * 64 + i * 16 + l15) * 32 + quad * 8];
        }
        #pragma unroll
        for (int i = 0; i < 4; ++i)
            #pragma unroll
            for (int j = 0; j < 4; ++j)
                acc[i][j] = __builtin_amdgcn_mfma_f32_16x16x32_bf16(
                                af[i], bf_[j], acc[i][j], 0, 0, 0);
    }

    if (EPI == 0) {
        #pragma unroll
        for (int i = 0; i < 4; ++i) {
            const int mrow = m0 + wm * 64 + i * 16 + quad * 4;
            #pragma unroll
            for (int j = 0; j < 4; ++j) {
                const int ncol = n0 + wn * 64 + j * 16 + l15;
                const float bb = bias[ncol];
                #pragma unroll
                for (int r = 0; r < 4; ++r)
                    store1(C + (size_t)(mrow + r) * ldc + ncol, acc[i][j][r] + bb);
            }
        }
    } else {
        const int head = n0 >> 8;
        const bool is_v = (n0 & 128) != 0;
        __syncthreads();   // main-loop LDS reads complete before overwrite
        #pragma unroll
        for (int p = 0; p < 2; ++p) {          // p = local ktile = wm
            if (p) __syncthreads();            // pass-0 copyout done
            if (wm == p) {
                #pragma unroll
                for (int i = 0; i < 4; ++i) {
                    #pragma unroll
                    for (int j = 0; j < 4; ++j) {
                        const int ncl = wn * 64 + j * 16 + l15;   // dim 0..127
                        const float bb = bias[n0 + ncl];
                        #pragma unroll
                        for (int r = 0; r < 4; ++r) {
                            const unsigned short v = f2bf(acc[i][j][r] + bb);
                            const int lnf = quad * 4 + r;          // tok%16
                            int off;
                            if (!is_v) {
                                const int s = ncl >> 5, qf = (ncl >> 3) & 3, e = ncl & 7;
                                off = (s * 4 + i) * 512 + (qf * 16 + lnf) * 8 + e;
                            } else {
                                const int nt = ncl >> 4, lnv = ncl & 15;
                                const int jj = i * 16 + lnf;       // tok%64
                                const int s2 = jj >> 5, qv = (jj >> 3) & 3, ev = jj & 7;
                                off = (nt * 2 + s2) * 512 + (qv * 16 + lnv) * 8 + ev;
                            }
                            smem[off] = v;
                        }
                    }
                }
            }
            __syncthreads();
            // coalesced copy: 16 KB fragment block -> kvf
            const size_t GT = (size_t)(m0 >> 6) + p;
            unsigned short* dst = kvf + ((GT * 16 + head) << 14) + (is_v ? 16 * 512 : 0);
            #pragma unroll
            for (int it = 0; it < 4; ++it) {
                const int u = (tid + it * 256) * 8;
                *(ushort8_t*)(dst + u) = *(const ushort8_t*)&smem[u];
            }
        }
    }
}

// ---------------------------------------------------------------------------
// Fused q-proj + kva-proj (same A operand, K=1024): one launch, branch on bx.
// ---------------------------------------------------------------------------
__global__ __launch_bounds__(256) void gemm_qkva(
    const __hip_bfloat16* __restrict__ A,
    const __hip_bfloat16* __restrict__ Wq, const float* __restrict__ biasq,
    __hip_bfloat16* __restrict__ Cq,
    const __hip_bfloat16* __restrict__ Wa, const float* __restrict__ biasa,
    __hip_bfloat16* __restrict__ Ca)
{
    __shared__ unsigned short smem[2 * 128 * 32];
    unsigned short* A_s = smem;
    unsigned short* B_s = smem + 128 * 32;

    const bool is_q = blockIdx.x < 24;
    const __hip_bfloat16* W = is_q ? Wq : Wa;
    const float* bias       = is_q ? biasq : biasa;
    __hip_bfloat16* C       = is_q ? Cq : Ca;
    const int ldc = is_q ? 3072 : 640;
    const int n0  = (is_q ? blockIdx.x : (blockIdx.x - 24)) * 128;
    const int m0  = blockIdx.y * 128;

    const int tid  = threadIdx.x;
    const int ln   = tid & 63;
    const int wv   = tid >> 6;
    const int l15  = ln & 15;
    const int quad = ln >> 4;
    const int wm   = wv & 1, wn = wv >> 1;

    v4f acc[4][4] = {};

    for (int k0 = 0; k0 < 1024; k0 += 32) {
        __syncthreads();
        #pragma unroll
        for (int it = 0; it < 2; ++it) {
            const int idx = it * 256 + wv * 64;
            const int li  = idx + ln;
            const int row = li >> 2, ch = li & 3;
            load_lds16(A + (size_t)(m0 + row) * 1024 + k0 + ch * 8, &A_s[idx * 8]);
            load_lds16(W + (size_t)(n0 + row) * 1024 + k0 + ch * 8, &B_s[idx * 8]);
        }
        __syncthreads();

        v8bf af[4], bf_[4];
        #pragma unroll
        for (int i = 0; i < 4; ++i) {
            af[i]  = *(const v8bf*)&A_s[(wm * 64 + i * 16 + l15) * 32 + quad * 8];
            bf_[i] = *(const v8bf*)&B_s[(wn * 64 + i * 16 + l15) * 32 + quad * 8];
        }
        #pragma unroll
        for (int i = 0; i < 4; ++i)
            #pragma unroll
            for (int j = 0; j < 4; ++j)
                acc[i][j] = __builtin_amdgcn_mfma_f32_16x16x32_bf16(
                                af[i], bf_[j], acc[i][j], 0, 0, 0);
    }

    #pragma unroll
    for (int i = 0; i < 4; ++i) {
        const int mrow = m0 + wm * 64 + i * 16 + quad * 4;
        #pragma unroll
        for (int j = 0; j < 4; ++j) {
            const int ncol = n0 + wn * 64 + j * 16 + l15;
            const float bb = bias[ncol];
            #pragma unroll
            for (int r = 0; r < 4; ++r)
                C[(size_t)(mrow + r) * ldc + ncol] = __float2bfloat16(acc[i][j][r] + bb);
        }
    }
}

// ---------------------------------------------------------------------------
// RMS-norm kv_a[:,0:512] -> kvn bf16; RoPE kv_a[:,512:576] -> kr bf16.
// ---------------------------------------------------------------------------
__global__ __launch_bounds__(256) void rmsnorm_ropek(
    const __hip_bfloat16* __restrict__ kva,
    __hip_bfloat16* __restrict__ kvn,
    __hip_bfloat16* __restrict__ kr,
    const float* __restrict__ cs,
    const float* __restrict__ sn)
{
    const int tok = blockIdx.x;
    const int tid = threadIdx.x;
    const __hip_bfloat16* row = kva + (size_t)tok * 640;

    const float x0 = __bfloat162float(row[tid]);
    const float x1 = __bfloat162float(row[tid + 256]);
    float ss = x0*x0 + x1*x1;
    #pragma unroll
    for (int off = 32; off >= 1; off >>= 1)
        ss += __shfl_down(ss, off);

    __shared__ float red[4];
    __shared__ float scale_sh;
    if ((tid & 63) == 0) red[tid >> 6] = ss;
    __syncthreads();
    if (tid == 0) {
        const float tot = red[0] + red[1] + red[2] + red[3];
        scale_sh = rsqrtf(tot * (1.0f/512.0f) + 1e-6f);
    }
    __syncthreads();
    const float sc = scale_sh;
    kvn[(size_t)tok*512 + tid]       = __float2bfloat16(x0 * sc);
    kvn[(size_t)tok*512 + tid + 256] = __float2bfloat16(x1 * sc);

    if (tid < 32) {
        const int t = tok & (T_ - 1);
        const float c = cs[t*32 + tid];
        const float s = sn[t*32 + tid];
        const float xr = __bfloat162float(row[KVR_ + 2*tid]);
        const float xi = __bfloat162float(row[KVR_ + 2*tid + 1]);
        kr[(size_t)tok*64 + 2*tid]     = __float2bfloat16(xr * c - xi * s);
        kr[(size_t)tok*64 + 2*tid + 1] = __float2bfloat16(xr * s + xi * c);
    }
}

// ---------------------------------------------------------------------------
// MFMA flash attention, BQ=256 / BK=64, 8 waves, two q-strips per wave.
// K/V staged from FRAGMENT-ORDERED global kvf: each fragment load is
// base + lane*16B -> 1 coalesced KB (was a 64-line scatter = the r11 stall).
// kr (head-shared, 1 MB) staged coalesced per-thread and fragment-ordered
// into LDS. Register-prefetch pipeline; base-2 softmax w/ raw v_exp_f32.
// LDS KVf slots: 0..15 = K_nope, 16..23 = kr, 24..39 = V.
// ---------------------------------------------------------------------------
__device__ __forceinline__ void attn_stage_regs(
    v8bf* R,
    const unsigned short* __restrict__ kvf,
    const __hip_bfloat16* __restrict__ kr,
    size_t tokb, int j0, int h, int wv, int lane, int tid)
{
    const size_t GT = (tokb + j0) >> 6;
    const unsigned short* base = kvf + ((GT * 16 + h) << 14);
    #pragma unroll
    for (int i = 0; i < 4; ++i)
        R[i] = *(const v8bf*)(base + ((wv * 4 + i) << 9) + lane * 8);
    // kr: thread (j=tid>>3, dch=tid&7) -> 16B coalesced
    const int j = tid >> 3, dch = tid & 7;
    R[4] = *(const v8bf*)((const unsigned short*)kr + (tokb + j0 + j) * 64 + dch * 8);
}

__global__ __launch_bounds__(512, 2) void attn_mfma(
    const __hip_bfloat16* __restrict__ q,
    const unsigned short* __restrict__ kvf,
    const __hip_bfloat16* __restrict__ kr,
    const float* __restrict__ cs,
    const float* __restrict__ sn,
    __hip_bfloat16* __restrict__ att)
{
    __shared__ unsigned short KVf[40 * 512];        // 40 KB
    __shared__ unsigned short P_s[8][2][16 * 72];   // 36 KB

    const int tid  = threadIdx.x;
    const int lane = tid & 63;
    const int ln   = tid & 15;
    const int quad = (tid >> 4) & 3;
    const int wv   = tid >> 6;                      // 0..7

    const int qt = (int)(gridDim.x - 1) - (int)blockIdx.x;  // longest first
    const int h  = blockIdx.y, b = blockIdx.z;
    const int q0 = qt * 256;
    const size_t tokb = (size_t)b * T_;

    // ---- Q fragments for both strips (A layout), fused RoPE + base2 scale ----
    v8bf qf[2][6];
    #pragma unroll
    for (int st = 0; st < 2; ++st) {
        const int trow = q0 + st*128 + wv*16 + ln;
        const __hip_bfloat16* qrow =
            q + (tokb + trow) * (size_t)(H_*QKD_) + h*QKD_;
        #pragma unroll
        for (int s = 0; s < 6; ++s) {
            ushort8_t raw = *(const ushort8_t*)(qrow + s*32 + quad*8);
            ushort8_t o;
            if (s < 4) {
                #pragma unroll
                for (int i = 0; i < 8; ++i)
                    o[i] = f2bf(bf2f(raw[i]) * SCALE2_);
            } else {
                #pragma unroll
                for (int p2 = 0; p2 < 4; ++p2) {
                    const int fi = (s-4)*16 + quad*4 + p2;
                    const float c  = cs[trow*32 + fi];
                    const float sv = sn[trow*32 + fi];
                    const float xr = bf2f(raw[p2*2]);
                    const float xi = bf2f(raw[p2*2+1]);
                    o[p2*2]   = f2bf((xr*c - xi*sv) * SCALE2_);
                    o[p2*2+1] = f2bf((xr*sv + xi*c) * SCALE2_);
                }
            }
            qf[st][s] = __builtin_bit_cast(v8bf, o);
        }
    }

    v4f O[2][8];
    #pragma unroll
    for (int st = 0; st < 2; ++st)
        #pragma unroll
        for (int nt = 0; nt < 8; ++nt) O[st][nt] = (v4f){0.f, 0.f, 0.f, 0.f};
    float m_r[2][4], l_r[2][4];
    #pragma unroll
    for (int st = 0; st < 2; ++st)
        #pragma unroll
        for (int r = 0; r < 4; ++r) { m_r[st][r] = -1e30f; l_r[st][r] = 0.0f; }

    const int qmin0 = q0 + wv*16;
    const int qmin1 = q0 + 128 + wv*16;
    const int nkt = (q0 + 256) >> 6;

    // LDS slot base for this wave's 4 kvf fragments (kn->0..15, V->24..39)
    const int slot0 = (wv < 4) ? (wv * 4) : (wv * 4 + 8);
    // kr LDS target for this thread
    const int krj = tid >> 3, krd = tid & 7;
    const int krfrag = 16 + (krd >> 2) * 4 + (krj >> 4);
    const int kroff  = krfrag * 512 + ((krd & 3) * 16 + (krj & 15)) * 8;

    // prefetch tile 0
    v8bf R[5];
    attn_stage_regs(R, kvf, kr, tokb, 0, h, wv, lane, tid);

    for (int kt = 0; kt < nkt; ++kt) {
        const int j0 = kt << 6;

        #pragma unroll
        for (int i = 0; i < 4; ++i)
            *(v8bf*)&KVf[(slot0 + i) * 512 + lane * 8] = R[i];
        *(v8bf*)&KVf[kroff] = R[4];
        __syncthreads();

        if (kt + 1 < nkt)
            attn_stage_regs(R, kvf, kr, tokb, j0 + 64, h, wv, lane, tid);

        const bool act0 = (j0 <= qmin0 + 15);   // wave-uniform
        const bool act1 = (j0 <= qmin1 + 15);

        if (act1) {
            // ---- S = Q K^T ----
            v4f S[2][4];
            #pragma unroll
            for (int st = 0; st < 2; ++st)
                #pragma unroll
                for (int t = 0; t < 4; ++t) S[st][t] = (v4f){0.f, 0.f, 0.f, 0.f};
            if (act0) {
                #pragma unroll
                for (int s = 0; s < 6; ++s)
                    #pragma unroll
                    for (int t = 0; t < 4; ++t) {
                        const v8bf kb = *(const v8bf*)&KVf[(s*4 + t)*512 + lane*8];
                        S[0][t] = __builtin_amdgcn_mfma_f32_16x16x32_bf16(qf[0][s], kb, S[0][t], 0, 0, 0);
                        S[1][t] = __builtin_amdgcn_mfma_f32_16x16x32_bf16(qf[1][s], kb, S[1][t], 0, 0, 0);
                    }
            } else {
                #pragma unroll
                for (int s = 0; s < 6; ++s)
                    #pragma unroll
                    for (int t = 0; t < 4; ++t) {
                        const v8bf kb = *(const v8bf*)&KVf[(s*4 + t)*512 + lane*8];
                        S[1][t] = __builtin_amdgcn_mfma_f32_16x16x32_bf16(qf[1][s], kb, S[1][t], 0, 0, 0);
                    }
            }

            // ---- per-strip mask + online softmax (base-2, hw exp) + P write ----
            float alpha[2][4];
            #pragma unroll
            for (int st = 0; st < 2; ++st) {
                if (st == 0 && !act0) continue;
                const int qmin = (st == 0) ? qmin0 : qmin1;
                if (j0 + 63 > qmin) {
                    #pragma unroll
                    for (int t = 0; t < 4; ++t) {
                        const int kpos = j0 + t*16 + ln;
                        #pragma unroll
                        for (int r = 0; r < 4; ++r)
                            if (kpos > qmin + quad*4 + r) S[st][t][r] = -1e30f;
                    }
                }
                #pragma unroll
                for (int r = 0; r < 4; ++r) {
                    float mx = fmaxf(fmaxf(S[st][0][r], S[st][1][r]),
                                     fmaxf(S[st][2][r], S[st][3][r]));
                    #pragma unroll
                    for (int off = 1; off < 16; off <<= 1)
                        mx = fmaxf(mx, __shfl_xor(mx, off));
                    const float mn = fmaxf(m_r[st][r], mx);
                    alpha[st][r] = exp2_hw(m_r[st][r] - mn);
                    m_r[st][r] = mn;
                }
                float rs[4] = {0.f, 0.f, 0.f, 0.f};
                #pragma unroll
                for (int t = 0; t < 4; ++t)
                    #pragma unroll
                    for (int r = 0; r < 4; ++r) {
                        const float pp = exp2_hw(S[st][t][r] - m_r[st][r]);
                        S[st][t][r] = pp;
                        rs[r] += pp;
                    }
                #pragma unroll
                for (int r = 0; r < 4; ++r) {
                    #pragma unroll
                    for (int off = 1; off < 16; off <<= 1)
                        rs[r] += __shfl_xor(rs[r], off);
                    l_r[st][r] = l_r[st][r]*alpha[st][r] + rs[r];
                }
                #pragma unroll
                for (int t = 0; t < 4; ++t)
                    #pragma unroll
                    for (int r = 0; r < 4; ++r)
                        P_s[wv][st][(quad*4 + r)*72 + t*16 + ln] = f2bf(S[st][t][r]);
                #pragma unroll
                for (int nt = 0; nt < 8; ++nt)
                    #pragma unroll
                    for (int r = 0; r < 4; ++r)
                        O[st][nt][r] *= alpha[st][r];
            }

            // ---- O += P V ----
            #pragma unroll
            for (int s2 = 0; s2 < 2; ++s2) {
                const v8bf pa1 = *(const v8bf*)&P_s[wv][1][ln*72 + s2*32 + quad*8];
                if (act0) {
                    const v8bf pa0 = *(const v8bf*)&P_s[wv][0][ln*72 + s2*32 + quad*8];
                    #pragma unroll
                    for (int nt = 0; nt < 8; ++nt) {
                        const v8bf vb = *(const v8bf*)&KVf[(24 + nt*2 + s2)*512 + lane*8];
                        O[0][nt] = __builtin_amdgcn_mfma_f32_16x16x32_bf16(pa0, vb, O[0][nt], 0, 0, 0);
                        O[1][nt] = __builtin_amdgcn_mfma_f32_16x16x32_bf16(pa1, vb, O[1][nt], 0, 0, 0);
                    }
                } else {
                    #pragma unroll
                    for (int nt = 0; nt < 8; ++nt) {
                        const v8bf vb = *(const v8bf*)&KVf[(24 + nt*2 + s2)*512 + lane*8];
                        O[1][nt] = __builtin_amdgcn_mfma_f32_16x16x32_bf16(pa1, vb, O[1][nt], 0, 0, 0);
                    }
                }
            }
        }
        __syncthreads();
    }

    // ---- epilogue: both strips ----
    #pragma unroll
    for (int st = 0; st < 2; ++st) {
        __hip_bfloat16* obase =
            att + (tokb + q0 + st*128 + wv*16) * (size_t)(H_*VDIM_) + h*VDIM_;
        #pragma unroll
        for (int r = 0; r < 4; ++r) {
            const float inv = 1.0f / l_r[st][r];
            __hip_bfloat16* orow = obase + (size_t)(quad*4 + r) * (H_*VDIM_);
            #pragma unroll
            for (int nt = 0; nt < 8; ++nt)
                orow[nt*16 + ln] = __float2bfloat16(O[st][nt][r] * inv);
        }
    }
}

// Diagnostic fallback
__global__ void fill_zero(float* p, int n) {
    int i = blockIdx.x * 256 + threadIdx.x;
    if (i < n) p[i] = 0.0f;
}

// ---------------------------------------------------------------------------
extern "C" void kernel_launch(void* const* d_in, const int* in_sizes, int n_in,
                              void* d_out, int out_size, void* d_ws, size_t ws_size,
                              hipStream_t stream)
{
    const float* x      = (const float*)d_in[0];
    const float* wq_w   = (const float*)d_in[1];
    const float* wq_b   = (const float*)d_in[2];
    const float* wkva_w = (const float*)d_in[3];
    const float* wkva_b = (const float*)d_in[4];
    const float* wkvb_w = (const float*)d_in[5];
    const float* wkvb_b = (const float*)d_in[6];
    const float* wo_w   = (const float*)d_in[7];
    const float* wo_b   = (const float*)d_in[8];
    const float* cs     = (const float*)d_in[9];
    const float* sn     = (const float*)d_in[10];

    const size_t q_b    = (size_t)NTOK * 3072 * 2;            // 50,331,648
    const size_t kvf_b  = (size_t)128 * 16 * 32 * 512 * 2;    // 67,108,864
    const size_t xb_b   = (size_t)NTOK * 1024 * 2;
    const size_t kvap_b = (size_t)NTOK * 640 * 2;
    const size_t kvn_b  = (size_t)NTOK * 512 * 2;
    const size_t wq_b_b = (size_t)3072 * 1024 * 2;            // kr aliases this
    const size_t wkva_b_b = (size_t)640 * 1024 * 2;
    const size_t wkvb_b_b = (size_t)4096 * 512 * 2;
    const size_t wo_b_b   = (size_t)1024 * 2048 * 2;
    const size_t bias_b   = 4096;
    const size_t need = q_b + kvf_b + xb_b + kvap_b + kvn_b +
                        wq_b_b + wkva_b_b + wkvb_b_b + wo_b_b + bias_b;

    if (ws_size < need) {
        fill_zero<<<(out_size + 255) / 256, 256, 0, stream>>>((float*)d_out, out_size);
        return;
    }

    char* p = (char*)d_ws;
    __hip_bfloat16* q    = (__hip_bfloat16*)p;             p += q_b;
    unsigned short* kvf  = (unsigned short*)p;             p += kvf_b;
    char*           dynr = p;
    __hip_bfloat16* xb   = (__hip_bfloat16*)p;             p += xb_b;
    __hip_bfloat16* kvap = (__hip_bfloat16*)p;             p += kvap_b;
    __hip_bfloat16* kvn  = (__hip_bfloat16*)p;             p += kvn_b;
    __hip_bfloat16* wq_bf = (__hip_bfloat16*)p;
    __hip_bfloat16* kr    = (__hip_bfloat16*)p;            p += wq_b_b;
    __hip_bfloat16* wkva_bf = (__hip_bfloat16*)p;          p += wkva_b_b;
    __hip_bfloat16* wkvb_bf = (__hip_bfloat16*)p;          p += wkvb_b_b;
    __hip_bfloat16* wo_bf   = (__hip_bfloat16*)p;          p += wo_b_b;
    float*          bias_pad = (float*)p;
    __hip_bfloat16* attb = (__hip_bfloat16*)dynr;
    float*          out  = (float*)d_out;

    // 1) all conversions, one launch
    cvt_all<<<CVT_TOTAL / 256, 256, 0, stream>>>(
        x, wq_w, wkvb_w, wo_w, wkva_w, wkva_b,
        xb, wq_bf, wkvb_bf, wo_bf, wkva_bf, bias_pad);

    // 2) fused q-proj + kva-proj (q-RoPE fused in attn)
    gemm_qkva<<<dim3(29, NTOK/128), 256, 0, stream>>>(
        xb, wq_bf, wq_b, q, wkva_bf, bias_pad, kvap);

    // 3) rmsnorm + rope-k  (kr overwrites wq_bf region — wq_bf dead after step 2)
    rmsnorm_ropek<<<NTOK, 256, 0, stream>>>(kvap, kvn, kr, cs, sn);

    // 4) kv_b -> fragment-ordered kvf (K_nope frags 0..15, V frags 16..31)
    gemm_mfma<__hip_bfloat16, 1><<<dim3(4096/128, NTOK/128), 256, 0, stream>>>(
        kvn, 512, wkvb_bf, 512, wkvb_b, (( __hip_bfloat16*)nullptr), 0, 512, kvf);

    // 5) attention: coalesced fragment staging
    attn_mfma<<<dim3(T_/256, H_, B_), 512, 0, stream>>>(q, kvf, kr, cs, sn, attb);

    // 6) out = att @ wo^T + b  (8192 x 1024, K=2048)
    gemm_mfma<float, 0><<<dim3(1024/128, NTOK/128), 256, 0, stream>>>(
        attb, 2048, wo_bf, 2048, wo_b, out, 1024, 2048, nullptr);
}